// Round 8
// baseline (10.682 us; speedup 1.0000x reference)
//
#include <hip/hip_runtime.h>
#include <math.h>

#define NLOC 21504
#define N3 16384
#define N4 4096
#define N5 1024
#define CHUNKS 42   // 42 chunks of 512 locations per batch, 8 waves/block
// p3: chunks 0..31  (4 rows x 128 cols), wave = 1 row x 64 cols (half-width)
// p4: chunks 32..39 (8 rows x 64 cols),  wave = 1 row x 64 cols
// p5: chunks 40..41 (16 rows x 32 cols), wave = 2 rows x 32 cols

typedef float vfloat4 __attribute__((ext_vector_type(4)));

__global__ __launch_bounds__(512) void fcos_assign(
    const float* __restrict__ gt,      // (16, 64, 5)
    const float* __restrict__ pred3,   // (16, 16384, 4)
    const float* __restrict__ pred4,   // (16, 4096, 4)
    const float* __restrict__ pred5,   // (16, 1024, 4)
    float* __restrict__ out)           // (16, 21504, 14)
{
    // Wave-private candidate lists and output staging: NO __syncthreads anywhere.
    __shared__ float scand[8][64][8];   // 16 KiB  [x0,y0,x1,y1,cls,q,-,-]
    __shared__ float sout[8][896];      // 28 KiB (64 locations x 14 ch per wave)

    const int tid   = threadIdx.x;
    const int lane  = tid & 63;
    const int w     = tid >> 6;
    const int b     = blockIdx.x / CHUNKS;
    const int chunk = blockIdx.x % CHUNKS;

    // ---- issue gt loads FIRST: longest-latency item on the pre-ballot path ----
    const float* g = gt + (size_t)b * 320 + lane * 5;
    const float bx0 = g[0], by0 = g[1], bx1 = g[2], by1 = g[3], bcl = g[4];

    // ---- per-thread location, computed arithmetically (bit-exact vs _grid:
    //      (col+0.5)*2^k is exact in f32) + wave-uniform level/window params ----
    const int i = chunk * 512 + tid;     // global location index in [0, 21504)
    float cx, cy, stride, lower, upper;
    float cx_min, cx_max, cy_min, cy_max;   // wave's location window
    const float* pred;
    if (chunk < 32) {                               // p3
        const int row = chunk * 4 + (w >> 1);
        const int col = (w & 1) * 64 + lane;
        cx = (col + 0.5f) * 8.0f;  cy = (row + 0.5f) * 8.0f;
        stride = 8.0f; lower = 0.0f; upper = 64.0f;
        cy_min = cy_max = cy;                       // 1 row per wave
        cx_min = ((w & 1) * 64 + 0.5f) * 8.0f;
        cx_max = ((w & 1) * 64 + 63.5f) * 8.0f;
        pred = pred3 + ((size_t)b * N3 + i) * 4;
    } else if (chunk < 40) {                        // p4
        const int il  = i - N3;
        const int row = (chunk - 32) * 8 + w;       // = il >> 6
        cx = (lane + 0.5f) * 16.0f;  cy = (row + 0.5f) * 16.0f;
        stride = 16.0f; lower = 64.0f; upper = 128.0f;
        cy_min = cy_max = cy;                       // 1 row per wave
        cx_min = 8.0f;  cx_max = 1016.0f;           // full width
        pred = pred4 + ((size_t)b * N4 + il) * 4;
    } else {                                        // p5
        const int il  = i - N3 - N4;
        const int row = il >> 5;                    // wave covers rows r0, r0+1
        const int col = lane & 31;
        cx = (col + 0.5f) * 32.0f;  cy = (row + 0.5f) * 32.0f;
        stride = 32.0f; lower = 128.0f; upper = INFINITY;
        const int r0 = (il - lane) >> 5;            // first row of this wave
        cy_min = (r0 + 0.5f) * 32.0f;  cy_max = (r0 + 1.5f) * 32.0f;
        cx_min = 16.0f;  cx_max = 1008.0f;          // full width
        pred = pred5 + ((size_t)b * N5 + il) * 4;
    }

    // ---- prefetch prediction, nontemporal (single-use, skip L2 retention) ----
    const vfloat4 p = __builtin_nontemporal_load((const vfloat4*)pred);

    // ---- per-wave candidate filter: lane <-> box, ballot-compact ----
    // Necessary conditions only (with 0.25px margin >> any f32 rounding of the
    // reference's direct per-location tests), so no matchable box is dropped.
    // Order-preserving compaction keeps jnp.argmax first-max-wins semantics.
    const float eps = 0.25f;
    const float ylo = fmaxf(by0, by1 - upper), yhi = fminf(by1, by0 + upper);
    const float xlo = fmaxf(bx0, bx1 - upper), xhi = fminf(bx1, bx0 + upper);
    const bool keep = (ylo < cy_max + eps) && (yhi > cy_min - eps)
                   && (xlo < cx_max + eps) && (xhi > cx_min - eps)
                   && (fmaxf(bx1 - bx0, by1 - by0) > lower - eps);
    const unsigned long long mball = __ballot(keep);
    const int cnt = (int)__popcll(mball);
    if (keep) {
        const int pos = (int)__popcll(mball & ((1ull << lane) - 1ull));
        scand[w][pos][0] = bx0; scand[w][pos][1] = by0;
        scand[w][pos][2] = bx1; scand[w][pos][3] = by1;
        scand[w][pos][4] = bcl;
        // Exactly match JAX: q = 1e8 - (x1-x0)*(y1-y0), no FMA contraction.
        scand[w][pos][5] = __fsub_rn(1.0e8f,
                            __fmul_rn(__fsub_rn(bx1, bx0), __fsub_rn(by1, by0)));
    }
    __builtin_amdgcn_wave_barrier();   // wave-synchronous LDS: pin write->read order

    // ---- match loop over candidates (first-max-wins == jnp.argmax) ----
    float best = 0.0f;
    int   bi   = -1;
    for (int j = 0; j < cnt; ++j) {
        const float4 bx = *(const float4*)&scand[w][j][0];  // broadcast ds_read_b128
        const float  q  = scand[w][j][5];
        const float dl = cx - bx.x;
        const float dt = cy - bx.y;
        const float dr = bx.z - cx;
        const float db = bx.w - cy;
        const float mn = fminf(fminf(dl, dt), fminf(dr, db));
        const float mx = fmaxf(fmaxf(dl, dt), fmaxf(dr, db));
        const bool upd = (mn > 0.0f) && (mx > lower) && (mx < upper) && (q > best);
        best = upd ? q : best;
        bi   = upd ? j : bi;
    }

    float m0, m1, m2, m3, m4;
    if (bi < 0) {
        m0 = m1 = m2 = m3 = m4 = -1.0f;
    } else {
        const float4 bb = *(const float4*)&scand[w][bi][0];
        m0 = bb.x; m1 = bb.y; m2 = bb.z; m3 = bb.w;
        m4 = scand[w][bi][4];
    }

    // ---- targets + centerness ----
    const bool bg = (m4 == -1.0f);
    float t0, t1, t2, t3, ctr;
    if (bg) {
        t0 = t1 = t2 = t3 = -1.0f;
        ctr = -1.0f;
    } else {
        t0 = (cx - m0) / stride;   // exact: stride is a power of two
        t1 = (cy - m1) / stride;
        t2 = (m2 - cx) / stride;
        t3 = (m3 - cy) / stride;
        const float num = fminf(t0, t2) * fminf(t1, t3);
        const float den = fmaxf(t0, t2) * fmaxf(t1, t3);
        ctr = sqrtf(num / den);
    }

    // ---- decode predictions ----
    const float d0 = cx - fmaxf(p.x, 0.0f) * stride;
    const float d1 = cy - fmaxf(p.y, 0.0f) * stride;
    const float d2 = cx + fmaxf(p.z, 0.0f) * stride;
    const float d3 = cy + fmaxf(p.w, 0.0f) * stride;

    // ---- wave-private staging, then coalesced nontemporal float4 stores ----
    float2* so2 = (float2*)&sout[w][lane * 14];
    so2[0] = make_float2(d0, d1);
    so2[1] = make_float2(d2, d3);
    so2[2] = make_float2(m0, m1);
    so2[3] = make_float2(m2, m3);
    so2[4] = make_float2(m4, t0);
    so2[5] = make_float2(t1, t2);
    so2[6] = make_float2(t3, ctr);
    __builtin_amdgcn_wave_barrier();

    // 64 locations x 14 ch = 896 floats = 224 float4 per wave, contiguous.
    // Full-line streaming writes: nontemporal (no L2 allocation).
    vfloat4* ob = (vfloat4*)(out + (((size_t)b * NLOC) + (size_t)chunk * 512 + w * 64) * 14);
    const vfloat4* sv = (const vfloat4*)&sout[w][0];
    __builtin_nontemporal_store(sv[lane],        &ob[lane]);
    __builtin_nontemporal_store(sv[64 + lane],   &ob[64 + lane]);
    __builtin_nontemporal_store(sv[128 + lane],  &ob[128 + lane]);
    if (lane < 32)
        __builtin_nontemporal_store(sv[192 + lane], &ob[192 + lane]);
}

extern "C" void kernel_launch(void* const* d_in, const int* in_sizes, int n_in,
                              void* d_out, int out_size, void* d_ws, size_t ws_size,
                              hipStream_t stream) {
    const float* gt = (const float*)d_in[3];
    const float* p3 = (const float*)d_in[4];
    const float* p4 = (const float*)d_in[5];
    const float* p5 = (const float*)d_in[6];
    float* out = (float*)d_out;

    dim3 grid(16 * CHUNKS);   // 672 blocks, each: one batch, 512 locations
    dim3 block(512);
    hipLaunchKernelGGL(fcos_assign, grid, block, 0, stream,
                       gt, p3, p4, p5, out);
}